// Round 3
// baseline (237.144 us; speedup 1.0000x reference)
//
#include <hip/hip_runtime.h>

#define SEQ   2048
#define HD    64
#define BK    64
#define BQ    128
#define NITER (SEQ / BK)
#define K2E   0.18033688f          // 0.125 * log2(e), folded into Q fragments
#define TILE_BYTES 8192            // 64 x 64 bf16

typedef __attribute__((ext_vector_type(4))) float f32x4;
typedef __attribute__((ext_vector_type(8))) short bf16x8;
typedef unsigned long long u64;
typedef __attribute__((ext_vector_type(2))) unsigned long long u64x2;

#define SB() __builtin_amdgcn_sched_barrier(0)

// fp32 -> bf16 round-to-nearest-even
__device__ __forceinline__ short f2b(float f) {
    unsigned u = __builtin_bit_cast(unsigned, f);
    u += 0x7fffu + ((u >> 16) & 1u);
    return (short)(u >> 16);
}

// XOR-swizzle: 16B granule permuted within each 128B row (K/V images)
__device__ __forceinline__ unsigned swz(unsigned row, unsigned byteoff) {
    unsigned g = ((row & 7u) ^ ((row >> 3) & 7u)) << 4;
    return row * 128u + (byteoff ^ g);
}

// async global->LDS DMA, 16B per lane (dest = uniform base + lane*16)
__device__ __forceinline__ void async16(void* l, const void* g) {
    __builtin_amdgcn_global_load_lds(
        (const __attribute__((address_space(1))) unsigned int*)g,
        (__attribute__((address_space(3))) unsigned int*)l, 16, 0, 0);
}

// ============ prep: K,V fp32 -> bf16 swizzled per-tile images in ws ============
__global__ __launch_bounds__(256, 4)
void prep_kv(const float* __restrict__ Kg, const float* __restrict__ Vg,
             short* __restrict__ Kb, short* __restrict__ Vb)
{
    __shared__ short ldsv[BK * HD];
    const int tid = threadIdx.x;
    const int t   = blockIdx.x;
    const int bh  = blockIdx.y;
    const int rr  = tid >> 3;
    const int d0  = (tid & 7) * 8;

    const float* Kt = Kg + ((size_t)bh * SEQ + t * BK) * HD;
    const float* Vt = Vg + ((size_t)bh * SEQ + t * BK) * HD;
    short* Kout = Kb + ((size_t)bh * NITER + t) * (TILE_BYTES / 2);
    short* Vout = Vb + ((size_t)bh * NITER + t) * (TILE_BYTES / 2);

    #pragma unroll
    for (int h = 0; h < 2; ++h) {
        const int r = rr + h * 32;
        f32x4 a = *(const f32x4*)(Kt + (size_t)r * HD + d0);
        f32x4 b = *(const f32x4*)(Kt + (size_t)r * HD + d0 + 4);
        bf16x8 v;
        #pragma unroll
        for (int j = 0; j < 4; ++j) { v[j] = f2b(a[j]); v[4 + j] = f2b(b[j]); }
        *(bf16x8*)((char*)Kout + swz(r, 2 * d0)) = v;

        f32x4 c = *(const f32x4*)(Vt + (size_t)r * HD + d0);
        f32x4 d = *(const f32x4*)(Vt + (size_t)r * HD + d0 + 4);
        #pragma unroll
        for (int j = 0; j < 4; ++j) {
            *(short*)((char*)ldsv + swz(d0 + j,     2 * r)) = f2b(c[j]);
            *(short*)((char*)ldsv + swz(d0 + 4 + j, 2 * r)) = f2b(d[j]);
        }
    }
    __syncthreads();
    const int off = tid * 16;
    *(f32x4*)((char*)Vout + off)        = *(const f32x4*)((const char*)ldsv + off);
    *(f32x4*)((char*)Vout + off + 4096) = *(const f32x4*)((const char*)ldsv + off + 4096);
}

// ===== prep: mask int32 -> bitmap MB[b][it][q], bit j = mask[b][q][it*64+j] =====
__global__ __launch_bounds__(256, 4)
void prep_mask(const int* __restrict__ Mg, unsigned long long* __restrict__ MB)
{
    const int tid  = threadIdx.x;
    const int lane = tid & 63;
    const int wv   = blockIdx.x * 4 + (tid >> 6);
    const int b    = wv >> 11;
    const int wvb  = wv & 2047;
    const int it   = wvb >> 6;
    const int qc   = (wvb & 63) * 32;
    const int k    = it * 64 + lane;

    const int* src = Mg + ((size_t)b * SEQ + qc) * SEQ + k;
    unsigned long long* dst = MB + ((size_t)b * NITER + it) * SEQ + qc;
    for (int i = 0; i < 32; ++i) {
        int mv = src[(size_t)i * SEQ];
        unsigned long long bits = __ballot(mv != 0);
        if (lane == 0) dst[i] = bits;
    }
}

// ================================ main kernel =================================
// 512 threads = 8 waves; each wave owns 16 q-rows (128 per block).
// Pass B computes S^T via swapped-operand MFMA so each lane holds 4 consecutive
// k-columns of one q-row -> f32x4 -> LDS transpose -> full-line dwordx4 stores
// (plain write-back path: full 128B lines, single-instruction coverage).
template<bool USE_MB>
__global__ __launch_bounds__(512, 4)
void attn_fwd(const float* __restrict__ Qg, const short* __restrict__ Kb,
              const short* __restrict__ Vb, const int* __restrict__ Mg,
              const unsigned long long* __restrict__ MB,
              float* __restrict__ Og, float* __restrict__ Pg)
{
    __shared__ short lds_kv[4][BK * HD];    // A: 4-deep K pipe; B: K dbuf(0,1) + V dbuf(2,3)
    __shared__ float lds_ps[8][16 * BK];    // wave-private fp32 P staging (4KB/wave)

    const int tid  = threadIdx.x;
    const int w    = tid >> 6;
    const int lane = tid & 63;
    const int l15  = lane & 15;
    const int l4   = lane >> 4;

    // XCD-aware bijective swizzle: 512 blocks -> 4 consecutive bh per XCD
    const int flat = blockIdx.x + (blockIdx.y << 4);
    const int nf   = ((flat & 7) << 6) | (flat >> 3);
    const int bh   = nf >> 4;
    const int qblk = nf & 15;
    const int b    = bh >> 4;
    const int qw   = qblk * BQ + w * 16;

    const float* Qp = Qg + (size_t)bh * SEQ * HD;
    const char*  Kt = (const char*)(Kb + (size_t)bh * NITER * (TILE_BYTES / 2));
    const char*  Vt = (const char*)(Vb + (size_t)bh * NITER * (TILE_BYTES / 2));
    const int*   Mp = Mg + (size_t)b * SEQ * SEQ;
    float*       Op = Og + (size_t)bh * SEQ * HD;
    float*       Pp = Pg + (size_t)bh * SEQ * SEQ;
    const u64*   MBq  = USE_MB ? MB + (size_t)b * NITER * SEQ + (qw + l4 * 4) : nullptr;
    const u64*   MBrw = USE_MB ? MB + (size_t)b * NITER * SEQ + (qw + l15)    : nullptr;

    // Q fragments pre-scaled by K2E: row qw+l15, k-dim d = c*32 + l4*8 + j
    bf16x8 qf[2];
    {
        const float* qrow = Qp + (size_t)(qw + l15) * HD + l4 * 8;
        #pragma unroll
        for (int c = 0; c < 2; ++c) {
            bf16x8 v;
            #pragma unroll
            for (int j = 0; j < 8; ++j) v[j] = f2b(qrow[c * 32 + j] * K2E);
            qf[c] = v;
        }
    }

    const int* mrow[4];
    #pragma unroll
    for (int r = 0; r < 4; ++r)
        mrow[r] = Mp + (size_t)(qw + l4 * 4 + r) * SEQ + l15;

    // 8 waves x 1KB = one 8KB tile per stage; exactly ONE VMEM op per wave
    auto stage_tile = [&](const char* gbase, int slot, int it) {
        const char* g = gbase + (size_t)it * TILE_BYTES + w * 1024 + lane * 16;
        char* l = (char*)lds_kv[slot] + w * 1024;
        async16(l, g);
    };

    // ---- pass A gate words: rows qw + l4*4 + r (4 u64 per lane) ----
    u64 curW[4], nxtW[4];
    auto loadW = [&](int it, u64* dst) {
        if constexpr (USE_MB) {
            const u64* mp = MBq + (size_t)it * SEQ;
            u64x2 a = *(const u64x2*)mp;
            u64x2 c = *(const u64x2*)(mp + 2);
            dst[0] = a[0]; dst[1] = a[1]; dst[2] = c[0]; dst[3] = c[1];
        }
    };
    unsigned gbit[4][4];   // pass A: [r][n]
    auto extract = [&](const u64* ws_, int it) {
        if constexpr (USE_MB) {
            #pragma unroll
            for (int r = 0; r < 4; ++r) {
                u64 wr = ws_[r] >> l15;
                unsigned lo = (unsigned)wr, hi = (unsigned)(wr >> 32);
                gbit[r][0] = lo & 1u;
                gbit[r][1] = lo & 0x10000u;
                gbit[r][2] = hi & 1u;
                gbit[r][3] = hi & 0x10000u;
            }
        } else {
            const int k0 = it * BK;
            #pragma unroll
            for (int r = 0; r < 4; ++r)
                #pragma unroll
                for (int n = 0; n < 4; ++n)
                    gbit[r][n] = (mrow[r][k0 + n * 16] != 0);
        }
    };
    auto rotW = [&]() {
        #pragma unroll
        for (int r = 0; r < 4; ++r) curW[r] = nxtW[r];
    };

    float lsum[4] = {0.f, 0.f, 0.f, 0.f};

    // ========== pass A: per-row denom, pinned 3-deep K pipeline ================
    stage_tile(Kt, 0, 0);           SB();
    loadW(0, curW);                 SB();
    stage_tile(Kt, 1, 1);           SB();
    stage_tile(Kt, 2, 2);           SB();
    for (int it = 0; it < NITER; ++it) {
        if constexpr (USE_MB) {
            if (it == 0)              asm volatile("s_waitcnt vmcnt(2)" ::: "memory");
            else if (it < NITER - 2)  asm volatile("s_waitcnt vmcnt(1)" ::: "memory");
            else                      asm volatile("s_waitcnt vmcnt(0)" ::: "memory");
        } else {
            if (it < NITER - 2)       asm volatile("s_waitcnt vmcnt(2)" ::: "memory");
            else if (it == NITER - 2) asm volatile("s_waitcnt vmcnt(1)" ::: "memory");
            else                      asm volatile("s_waitcnt vmcnt(0)" ::: "memory");
        }
        __builtin_amdgcn_s_barrier();
        SB();
        if (it + 1 < NITER) loadW(it + 1, nxtW);
        SB();
        if (it + 3 < NITER) stage_tile(Kt, (it + 3) & 3, it + 3);
        SB();

        extract(curW, it);

        const char* kbase = (const char*)lds_kv[it & 3];
        f32x4 sA[4];
        #pragma unroll
        for (int n = 0; n < 4; ++n) {
            f32x4 acc = {0.f, 0.f, 0.f, 0.f};
            #pragma unroll
            for (int c = 0; c < 2; ++c) {
                bf16x8 kf = *(const bf16x8*)(kbase +
                                swz(n * 16 + l15, (unsigned)(c * 64 + l4 * 16)));
                acc = __builtin_amdgcn_mfma_f32_16x16x32_bf16(qf[c], kf, acc, 0, 0, 0);
            }
            sA[n] = acc;
        }
        #pragma unroll
        for (int r = 0; r < 4; ++r) {
            #pragma unroll
            for (int n = 0; n < 4; ++n) {
                float e = exp2f(sA[n][r]);
                lsum[r] += gbit[r][n] ? e : 0.f;
            }
        }
        rotW();
    }

    // single cross-lane reduce; fold 1/l as additive -log2(l)
    float cl[4];
    #pragma unroll
    for (int r = 0; r < 4; ++r) {
        float s = lsum[r];
        s += __shfl_xor(s, 1);
        s += __shfl_xor(s, 2);
        s += __shfl_xor(s, 4);
        s += __shfl_xor(s, 8);
        cl[r] = -log2f(s);
    }
    // broadcast: clb = cl for q-row (qw + l15); source lane l4' = l15>>2, reg = l15&3
    float clb;
    {
        const int src = (l15 >> 2) << 4;
        float t0 = __shfl(cl[0], src);
        float t1 = __shfl(cl[1], src);
        float t2 = __shfl(cl[2], src);
        float t3 = __shfl(cl[3], src);
        float ca = (l15 & 1) ? t1 : t0;
        float cb = (l15 & 1) ? t3 : t2;
        clb = (l15 & 2) ? cb : ca;
    }

    f32x4 accO[4];
    #pragma unroll
    for (int n = 0; n < 4; ++n) accO[n] = (f32x4){0.f, 0.f, 0.f, 0.f};

    // ========== pass B: S^T recompute, LDS-transposed full-line P, O = P.V =====
    u64 curB = 0, nxtB = 0;
    auto loadB = [&](int it, u64& d) {
        if constexpr (USE_MB) d = *(const u64*)(MBrw + (size_t)it * SEQ);
    };
    unsigned gb[4][4];   // pass B: [n][r], k = n*16 + l4*4 + r of q-row (qw+l15)
    auto extractB = [&](u64 wd, int it) {
        if constexpr (USE_MB) {
            #pragma unroll
            for (int r = 0; r < 4; ++r) {
                u64 wr = wd >> (l4 * 4 + r);
                unsigned lo = (unsigned)wr, hi = (unsigned)(wr >> 32);
                gb[0][r] = lo & 1u;
                gb[1][r] = lo & 0x10000u;
                gb[2][r] = hi & 1u;
                gb[3][r] = hi & 0x10000u;
            }
        } else {
            const int* mB = Mp + (size_t)(qw + l15) * SEQ + l4 * 4 + it * BK;
            #pragma unroll
            for (int n = 0; n < 4; ++n)
                #pragma unroll
                for (int r = 0; r < 4; ++r)
                    gb[n][r] = (mB[n * 16 + r] != 0);
        }
    };

    char* psb = (char*)lds_ps[w];

    // Per iter pinned issue: [W|K|V](3 ops) ... 4 dwordx4 stores ... vmcnt(4):
    // retires the 3 stages + prev stores, keeps only this iter's 4 stores.
    loadB(0, curB);                 SB();
    stage_tile(Kt, 0, 0);           SB();
    stage_tile(Vt, 2, 0);           SB();
    asm volatile("s_waitcnt vmcnt(0)" ::: "memory");
    __builtin_amdgcn_s_barrier();
    SB();
    int cur = 0;
    for (int it = 0; it < NITER; ++it) {
        const int k0 = it * BK;
        if (it + 1 < NITER) {
            loadB(it + 1, nxtB);                  SB();
            stage_tile(Kt, cur ^ 1, it + 1);      SB();
            stage_tile(Vt, 2 + (cur ^ 1), it + 1);
        }
        SB();

        extractB(curB, it);

        // S^T: mfma(K, Q) -> col = q-row (l15), row = k-index (l4*4 + reg)
        const char* kbase = (const char*)lds_kv[cur];
        f32x4 sA[4];
        #pragma unroll
        for (int n = 0; n < 4; ++n) {
            f32x4 acc = {0.f, 0.f, 0.f, 0.f};
            #pragma unroll
            for (int c = 0; c < 2; ++c) {
                bf16x8 kf = *(const bf16x8*)(kbase +
                                swz(n * 16 + l15, (unsigned)(c * 64 + l4 * 16)));
                acc = __builtin_amdgcn_mfma_f32_16x16x32_bf16(kf, qf[c], acc, 0, 0, 0);
            }
            sA[n] = acc;
        }

        // p quads -> fp32 LDS (row = l15, granule (n*4+l4) ^ row)
        #pragma unroll
        for (int n = 0; n < 4; ++n) {
            f32x4 pq;
            #pragma unroll
            for (int r = 0; r < 4; ++r) {
                float e = exp2f(sA[n][r] + clb);
                pq[r] = gb[n][r] ? e : 0.f;
            }
            *(f32x4*)(psb + l15 * 256 +
                      ((((unsigned)(n * 4 + l4)) ^ (unsigned)l15) << 4)) = pq;
        }
        asm volatile("s_waitcnt lgkmcnt(0)" ::: "memory");
        SB();

        // readback rows (i*4+l4), cols l15*4..+3 -> dwordx4: 256B/row segments
        f32x4 tq[4];
        #pragma unroll
        for (int i = 0; i < 4; ++i) {
            const unsigned row = (unsigned)(i * 4 + l4);
            tq[i] = *(const f32x4*)(psb + row * 256 + (((unsigned)l15 ^ row) << 4));
        }
        #pragma unroll
        for (int i = 0; i < 4; ++i) {
            *(f32x4*)(Pp + (size_t)(qw + i * 4 + l4) * SEQ + k0 + l15 * 4) = tq[i];
        }
        SB();

        // O(16x64) += P(16x64) . V(64x64); pf from fp32 staging + f2b
        const char* vbase = (const char*)lds_kv[2 + cur];
        #pragma unroll
        for (int c = 0; c < 2; ++c) {
            const unsigned gb0 = (unsigned)(c * 8 + l4 * 2);
            f32x4 pa = *(const f32x4*)(psb + l15 * 256 + ((gb0 ^ (unsigned)l15) << 4));
            f32x4 pb = *(const f32x4*)(psb + l15 * 256 + (((gb0 + 1u) ^ (unsigned)l15) << 4));
            bf16x8 pf;
            #pragma unroll
            for (int j = 0; j < 4; ++j) { pf[j] = f2b(pa[j]); pf[4 + j] = f2b(pb[j]); }
            #pragma unroll
            for (int n2 = 0; n2 < 4; ++n2) {
                bf16x8 vf = *(const bf16x8*)(vbase +
                                swz(n2 * 16 + l15, (unsigned)(c * 64 + l4 * 16)));
                accO[n2] = __builtin_amdgcn_mfma_f32_16x16x32_bf16(pf, vf, accO[n2], 0, 0, 0);
            }
        }
        SB();
        asm volatile("s_waitcnt vmcnt(4)" ::: "memory");
        asm volatile("s_waitcnt lgkmcnt(0)" ::: "memory");
        __builtin_amdgcn_s_barrier();
        SB();
        curB = nxtB;
        cur ^= 1;
    }

    #pragma unroll
    for (int n2 = 0; n2 < 4; ++n2) {
        #pragma unroll
        for (int r = 0; r < 4; ++r) {
            Op[(size_t)(qw + l4 * 4 + r) * HD + n2 * 16 + l15] = accO[n2][r];
        }
    }
}

extern "C" void kernel_launch(void* const* d_in, const int* in_sizes, int n_in,
                              void* d_out, int out_size, void* d_ws, size_t ws_size,
                              hipStream_t stream) {
    const float* Q = (const float*)d_in[0];
    const float* K = (const float*)d_in[1];
    const float* V = (const float*)d_in[2];
    const int*   M = (const int*)d_in[3];
    float* O = (float*)d_out;
    float* P = O + (size_t)2 * 16 * 2048 * 64;

    const size_t half = (size_t)32 * NITER * TILE_BYTES;            // 8 MB
    const size_t mb_bytes = (size_t)2 * NITER * SEQ * 8;            // 1 MB
    short* Kb = (short*)d_ws;
    short* Vb = (short*)((char*)d_ws + half);
    prep_kv<<<dim3(NITER, 32), 256, 0, stream>>>(K, V, Kb, Vb);

    if (ws_size >= 2 * half + mb_bytes) {
        unsigned long long* MBp = (unsigned long long*)((char*)d_ws + 2 * half);
        prep_mask<<<1024, 256, 0, stream>>>(M, MBp);
        attn_fwd<true><<<dim3(SEQ / BQ, 32), 512, 0, stream>>>(Q, Kb, Vb, M, MBp, O, P);
    } else {
        attn_fwd<false><<<dim3(SEQ / BQ, 32), 512, 0, stream>>>(Q, Kb, Vb, M, nullptr, O, P);
    }
}

// Round 4
// 188.636 us; speedup vs baseline: 1.2572x; 1.2572x over previous
//
#include <hip/hip_runtime.h>

#define SEQ   2048
#define HD    64
#define BK    64
#define BQ    128
#define NITER (SEQ / BK)
#define K2E   0.18033688f          // 0.125 * log2(e), folded into Q fragments
#define TILE_BYTES 8192            // 64 x 64 bf16

typedef __attribute__((ext_vector_type(4))) float f32x4;
typedef __attribute__((ext_vector_type(8))) short bf16x8;
typedef unsigned long long u64;
typedef __attribute__((ext_vector_type(2))) unsigned long long u64x2;

#define SB() __builtin_amdgcn_sched_barrier(0)

// fp32 -> bf16 round-to-nearest-even
__device__ __forceinline__ short f2b(float f) {
    unsigned u = __builtin_bit_cast(unsigned, f);
    u += 0x7fffu + ((u >> 16) & 1u);
    return (short)(u >> 16);
}

// XOR-swizzle: 16B granule permuted within each 128B row (K/V images)
__device__ __forceinline__ unsigned swz(unsigned row, unsigned byteoff) {
    unsigned g = ((row & 7u) ^ ((row >> 3) & 7u)) << 4;
    return row * 128u + (byteoff ^ g);
}

// async global->LDS DMA, 16B per lane (dest = uniform base + lane*16)
__device__ __forceinline__ void async16(void* l, const void* g) {
    __builtin_amdgcn_global_load_lds(
        (const __attribute__((address_space(1))) unsigned int*)g,
        (__attribute__((address_space(3))) unsigned int*)l, 16, 0, 0);
}

// ============ prep: K,V fp32 -> bf16 swizzled per-tile images in ws ============
__global__ __launch_bounds__(256, 4)
void prep_kv(const float* __restrict__ Kg, const float* __restrict__ Vg,
             short* __restrict__ Kb, short* __restrict__ Vb)
{
    __shared__ short ldsv[BK * HD];
    const int tid = threadIdx.x;
    const int t   = blockIdx.x;
    const int bh  = blockIdx.y;
    const int rr  = tid >> 3;
    const int d0  = (tid & 7) * 8;

    const float* Kt = Kg + ((size_t)bh * SEQ + t * BK) * HD;
    const float* Vt = Vg + ((size_t)bh * SEQ + t * BK) * HD;
    short* Kout = Kb + ((size_t)bh * NITER + t) * (TILE_BYTES / 2);
    short* Vout = Vb + ((size_t)bh * NITER + t) * (TILE_BYTES / 2);

    #pragma unroll
    for (int h = 0; h < 2; ++h) {
        const int r = rr + h * 32;
        f32x4 a = *(const f32x4*)(Kt + (size_t)r * HD + d0);
        f32x4 b = *(const f32x4*)(Kt + (size_t)r * HD + d0 + 4);
        bf16x8 v;
        #pragma unroll
        for (int j = 0; j < 4; ++j) { v[j] = f2b(a[j]); v[4 + j] = f2b(b[j]); }
        *(bf16x8*)((char*)Kout + swz(r, 2 * d0)) = v;

        f32x4 c = *(const f32x4*)(Vt + (size_t)r * HD + d0);
        f32x4 d = *(const f32x4*)(Vt + (size_t)r * HD + d0 + 4);
        #pragma unroll
        for (int j = 0; j < 4; ++j) {
            *(short*)((char*)ldsv + swz(d0 + j,     2 * r)) = f2b(c[j]);
            *(short*)((char*)ldsv + swz(d0 + 4 + j, 2 * r)) = f2b(d[j]);
        }
    }
    __syncthreads();
    const int off = tid * 16;
    *(f32x4*)((char*)Vout + off)        = *(const f32x4*)((const char*)ldsv + off);
    *(f32x4*)((char*)Vout + off + 4096) = *(const f32x4*)((const char*)ldsv + off + 4096);
}

// ===== prep: mask int32 -> bitmap MB[b][it][q], bit j = mask[b][q][it*64+j] =====
__global__ __launch_bounds__(256, 4)
void prep_mask(const int* __restrict__ Mg, unsigned long long* __restrict__ MB)
{
    const int tid  = threadIdx.x;
    const int lane = tid & 63;
    const int wv   = blockIdx.x * 4 + (tid >> 6);
    const int b    = wv >> 11;
    const int wvb  = wv & 2047;
    const int it   = wvb >> 6;
    const int qc   = (wvb & 63) * 32;
    const int k    = it * 64 + lane;

    const int* src = Mg + ((size_t)b * SEQ + qc) * SEQ + k;
    unsigned long long* dst = MB + ((size_t)b * NITER + it) * SEQ + qc;
    for (int i = 0; i < 32; ++i) {
        int mv = src[(size_t)i * SEQ];
        unsigned long long bits = __ballot(mv != 0);
        if (lane == 0) dst[i] = bits;
    }
}

// ================================ main kernel =================================
// 512 threads = 8 waves; each wave owns 16 q-rows (128 per block).
// Pass B: S^T via swapped MFMA -> f32x4 per lane -> LDS transpose -> full-line
// NT dwordx4 stores. K/V staged 2 iters ahead (3-deep each) so the pre-barrier
// wait is vmcnt(11): keeps 3 store batches (3KB/wave) in flight across barriers.
template<bool USE_MB>
__global__ __launch_bounds__(512, 4)
void attn_fwd(const float* __restrict__ Qg, const short* __restrict__ Kb,
              const short* __restrict__ Vb, const int* __restrict__ Mg,
              const unsigned long long* __restrict__ MB,
              float* __restrict__ Og, float* __restrict__ Pg)
{
    extern __shared__ char smem[];                       // 81920 B dynamic
    short (*lds_kv)[BK * HD] = (short (*)[BK * HD])smem;          // 6 x 8KB
    float (*lds_ps)[16 * BK] = (float (*)[16 * BK])(smem + 6 * TILE_BYTES); // 8 x 4KB

    const int tid  = threadIdx.x;
    const int w    = tid >> 6;
    const int lane = tid & 63;
    const int l15  = lane & 15;
    const int l4   = lane >> 4;

    // XCD-aware bijective swizzle: 512 blocks -> 4 consecutive bh per XCD
    const int flat = blockIdx.x + (blockIdx.y << 4);
    const int nf   = ((flat & 7) << 6) | (flat >> 3);
    const int bh   = nf >> 4;
    const int qblk = nf & 15;
    const int b    = bh >> 4;
    const int qw   = qblk * BQ + w * 16;

    const float* Qp = Qg + (size_t)bh * SEQ * HD;
    const char*  Kt = (const char*)(Kb + (size_t)bh * NITER * (TILE_BYTES / 2));
    const char*  Vt = (const char*)(Vb + (size_t)bh * NITER * (TILE_BYTES / 2));
    const int*   Mp = Mg + (size_t)b * SEQ * SEQ;
    float*       Op = Og + (size_t)bh * SEQ * HD;
    float*       Pp = Pg + (size_t)bh * SEQ * SEQ;
    const u64*   MBq  = USE_MB ? MB + (size_t)b * NITER * SEQ + (qw + l4 * 4) : nullptr;
    const u64*   MBrw = USE_MB ? MB + (size_t)b * NITER * SEQ + (qw + l15)    : nullptr;

    // Q fragments pre-scaled by K2E: row qw+l15, k-dim d = c*32 + l4*8 + j
    bf16x8 qf[2];
    {
        const float* qrow = Qp + (size_t)(qw + l15) * HD + l4 * 8;
        #pragma unroll
        for (int c = 0; c < 2; ++c) {
            bf16x8 v;
            #pragma unroll
            for (int j = 0; j < 8; ++j) v[j] = f2b(qrow[c * 32 + j] * K2E);
            qf[c] = v;
        }
    }

    const int* mrow[4];
    #pragma unroll
    for (int r = 0; r < 4; ++r)
        mrow[r] = Mp + (size_t)(qw + l4 * 4 + r) * SEQ + l15;

    // 8 waves x 1KB = one 8KB tile per stage; exactly ONE VMEM op per wave
    auto stage_tile = [&](const char* gbase, int slot, int it) {
        const char* g = gbase + (size_t)it * TILE_BYTES + w * 1024 + lane * 16;
        char* l = (char*)lds_kv[slot] + w * 1024;
        async16(l, g);
    };

    // ---- pass A gate words: rows qw + l4*4 + r (4 u64 per lane) ----
    u64 curW[4], nxtW[4];
    auto loadW = [&](int it, u64* dst) {
        if constexpr (USE_MB) {
            const u64* mp = MBq + (size_t)it * SEQ;
            u64x2 a = *(const u64x2*)mp;
            u64x2 c = *(const u64x2*)(mp + 2);
            dst[0] = a[0]; dst[1] = a[1]; dst[2] = c[0]; dst[3] = c[1];
        }
    };
    unsigned gbit[4][4];   // pass A: [r][n]
    auto extract = [&](const u64* ws_, int it) {
        if constexpr (USE_MB) {
            #pragma unroll
            for (int r = 0; r < 4; ++r) {
                u64 wr = ws_[r] >> l15;
                unsigned lo = (unsigned)wr, hi = (unsigned)(wr >> 32);
                gbit[r][0] = lo & 1u;
                gbit[r][1] = lo & 0x10000u;
                gbit[r][2] = hi & 1u;
                gbit[r][3] = hi & 0x10000u;
            }
        } else {
            const int k0 = it * BK;
            #pragma unroll
            for (int r = 0; r < 4; ++r)
                #pragma unroll
                for (int n = 0; n < 4; ++n)
                    gbit[r][n] = (mrow[r][k0 + n * 16] != 0);
        }
    };
    auto rotW = [&]() {
        #pragma unroll
        for (int r = 0; r < 4; ++r) curW[r] = nxtW[r];
    };

    float lsum[4] = {0.f, 0.f, 0.f, 0.f};

    // ========== pass A: per-row denom, pinned 3-deep K pipeline ================
    stage_tile(Kt, 0, 0);           SB();
    loadW(0, curW);                 SB();
    stage_tile(Kt, 1, 1);           SB();
    stage_tile(Kt, 2, 2);           SB();
    for (int it = 0; it < NITER; ++it) {
        if constexpr (USE_MB) {
            if (it == 0)              asm volatile("s_waitcnt vmcnt(2)" ::: "memory");
            else if (it < NITER - 2)  asm volatile("s_waitcnt vmcnt(1)" ::: "memory");
            else                      asm volatile("s_waitcnt vmcnt(0)" ::: "memory");
        } else {
            if (it < NITER - 2)       asm volatile("s_waitcnt vmcnt(2)" ::: "memory");
            else if (it == NITER - 2) asm volatile("s_waitcnt vmcnt(1)" ::: "memory");
            else                      asm volatile("s_waitcnt vmcnt(0)" ::: "memory");
        }
        __builtin_amdgcn_s_barrier();
        SB();
        if (it + 1 < NITER) loadW(it + 1, nxtW);
        SB();
        if (it + 3 < NITER) stage_tile(Kt, (it + 3) & 3, it + 3);
        SB();

        extract(curW, it);

        const char* kbase = (const char*)lds_kv[it & 3];
        f32x4 sA[4];
        #pragma unroll
        for (int n = 0; n < 4; ++n) {
            f32x4 acc = {0.f, 0.f, 0.f, 0.f};
            #pragma unroll
            for (int c = 0; c < 2; ++c) {
                bf16x8 kf = *(const bf16x8*)(kbase +
                                swz(n * 16 + l15, (unsigned)(c * 64 + l4 * 16)));
                acc = __builtin_amdgcn_mfma_f32_16x16x32_bf16(qf[c], kf, acc, 0, 0, 0);
            }
            sA[n] = acc;
        }
        #pragma unroll
        for (int r = 0; r < 4; ++r) {
            #pragma unroll
            for (int n = 0; n < 4; ++n) {
                float e = exp2f(sA[n][r]);
                lsum[r] += gbit[r][n] ? e : 0.f;
            }
        }
        rotW();
    }

    // single cross-lane reduce; fold 1/l as additive -log2(l)
    float cl[4];
    #pragma unroll
    for (int r = 0; r < 4; ++r) {
        float s = lsum[r];
        s += __shfl_xor(s, 1);
        s += __shfl_xor(s, 2);
        s += __shfl_xor(s, 4);
        s += __shfl_xor(s, 8);
        cl[r] = -log2f(s);
    }
    // broadcast: clb = cl for q-row (qw + l15); source lane l4' = l15>>2, reg = l15&3
    float clb;
    {
        const int src = (l15 >> 2) << 4;
        float t0 = __shfl(cl[0], src);
        float t1 = __shfl(cl[1], src);
        float t2 = __shfl(cl[2], src);
        float t3 = __shfl(cl[3], src);
        float ca = (l15 & 1) ? t1 : t0;
        float cb = (l15 & 1) ? t3 : t2;
        clb = (l15 & 2) ? cb : ca;
    }

    f32x4 accO[4];
    #pragma unroll
    for (int n = 0; n < 4; ++n) accO[n] = (f32x4){0.f, 0.f, 0.f, 0.f};

    // ========== pass B: S^T recompute, LDS transpose, NT stores, O = P.V =======
    // 3-deep K (slots 0..2) + 3-deep V (slots 3..5), staged 2 iters ahead.
    // Steady wait vmcnt(11) retires only WKV(it+1); keeps 3 store batches live.
    u64 gA = 0, gB = 0, gC = 0;
    auto loadB = [&](int it, u64& d) {
        if constexpr (USE_MB) d = *(const u64*)(MBrw + (size_t)it * SEQ);
    };
    unsigned gb[4][4];   // pass B: [n][r], k = n*16 + l4*4 + r of q-row (qw+l15)
    auto extractB = [&](u64 wd, int it) {
        if constexpr (USE_MB) {
            #pragma unroll
            for (int r = 0; r < 4; ++r) {
                u64 wr = wd >> (l4 * 4 + r);
                unsigned lo = (unsigned)wr, hi = (unsigned)(wr >> 32);
                gb[0][r] = lo & 1u;
                gb[1][r] = lo & 0x10000u;
                gb[2][r] = hi & 1u;
                gb[3][r] = hi & 0x10000u;
            }
        } else {
            const int* mB = Mp + (size_t)(qw + l15) * SEQ + l4 * 4 + it * BK;
            #pragma unroll
            for (int n = 0; n < 4; ++n)
                #pragma unroll
                for (int r = 0; r < 4; ++r)
                    gb[n][r] = (mB[n * 16 + r] != 0);
        }
    };

    char* psb = (char*)lds_ps[w];

    int ks  = 0;   // slot of current iter (mod 3)
    int ks2 = 2;   // slot for staging it+2

    loadB(0, gA);                   SB();
    stage_tile(Kt, 0, 0);           SB();
    stage_tile(Vt, 3, 0);           SB();
    loadB(1, gB);                   SB();
    stage_tile(Kt, 1, 1);           SB();
    stage_tile(Vt, 4, 1);           SB();
    if constexpr (USE_MB) asm volatile("s_waitcnt vmcnt(3)" ::: "memory");
    else                  asm volatile("s_waitcnt vmcnt(2)" ::: "memory");
    __builtin_amdgcn_s_barrier();
    SB();
    for (int it = 0; it < NITER; ++it) {
        const int k0 = it * BK;
        if (it + 2 < NITER) {
            loadB(it + 2, gC);                SB();
            stage_tile(Kt, ks2, it + 2);      SB();
            stage_tile(Vt, 3 + ks2, it + 2);
        }
        SB();

        extractB(gA, it);

        // S^T: mfma(K, Q) -> col = q-row (l15), row = k-index (l4*4 + reg)
        const char* kbase = (const char*)lds_kv[ks];
        f32x4 sA[4];
        #pragma unroll
        for (int n = 0; n < 4; ++n) {
            f32x4 acc = {0.f, 0.f, 0.f, 0.f};
            #pragma unroll
            for (int c = 0; c < 2; ++c) {
                bf16x8 kf = *(const bf16x8*)(kbase +
                                swz(n * 16 + l15, (unsigned)(c * 64 + l4 * 16)));
                acc = __builtin_amdgcn_mfma_f32_16x16x32_bf16(kf, qf[c], acc, 0, 0, 0);
            }
            sA[n] = acc;
        }

        // p quads -> fp32 LDS (row = l15, granule (n*4+l4) ^ row)
        #pragma unroll
        for (int n = 0; n < 4; ++n) {
            f32x4 pq;
            #pragma unroll
            for (int r = 0; r < 4; ++r) {
                float e = exp2f(sA[n][r] + clb);
                pq[r] = gb[n][r] ? e : 0.f;
            }
            *(f32x4*)(psb + l15 * 256 +
                      ((((unsigned)(n * 4 + l4)) ^ (unsigned)l15) << 4)) = pq;
        }
        asm volatile("s_waitcnt lgkmcnt(0)" ::: "memory");
        SB();

        // readback rows (i*4+l4), cols l15*4..+3 -> NT dwordx4: 256B/row segments
        f32x4 tq[4];
        #pragma unroll
        for (int i = 0; i < 4; ++i) {
            const unsigned row = (unsigned)(i * 4 + l4);
            tq[i] = *(const f32x4*)(psb + row * 256 + (((unsigned)l15 ^ row) << 4));
        }
        #pragma unroll
        for (int i = 0; i < 4; ++i) {
            __builtin_nontemporal_store(tq[i],
                (f32x4*)(Pp + (size_t)(qw + i * 4 + l4) * SEQ + k0 + l15 * 4));
        }
        SB();

        // O(16x64) += P(16x64) . V(64x64); pf from fp32 staging + f2b
        const char* vbase = (const char*)lds_kv[3 + ks];
        #pragma unroll
        for (int c = 0; c < 2; ++c) {
            const unsigned gb0 = (unsigned)(c * 8 + l4 * 2);
            f32x4 pa = *(const f32x4*)(psb + l15 * 256 + ((gb0 ^ (unsigned)l15) << 4));
            f32x4 pb = *(const f32x4*)(psb + l15 * 256 + (((gb0 + 1u) ^ (unsigned)l15) << 4));
            bf16x8 pf;
            #pragma unroll
            for (int j = 0; j < 4; ++j) { pf[j] = f2b(pa[j]); pf[4 + j] = f2b(pb[j]); }
            #pragma unroll
            for (int n2 = 0; n2 < 4; ++n2) {
                bf16x8 vf = *(const bf16x8*)(vbase +
                                swz(n2 * 16 + l15, (unsigned)(c * 64 + l4 * 16)));
                accO[n2] = __builtin_amdgcn_mfma_f32_16x16x32_bf16(pf, vf, accO[n2], 0, 0, 0);
            }
        }
        SB();
        asm volatile("s_waitcnt lgkmcnt(0)" ::: "memory");
        if (it + 1 < NITER) {
            if (it == 0)              asm volatile("s_waitcnt vmcnt(7)"  ::: "memory");
            else if (it < NITER - 2)  asm volatile("s_waitcnt vmcnt(11)" ::: "memory");
            else                      asm volatile("s_waitcnt vmcnt(8)"  ::: "memory");
            __builtin_amdgcn_s_barrier();
        }
        SB();
        gA = gB; gB = gC;
        ks  = (ks  + 1 == 3) ? 0 : ks  + 1;
        ks2 = (ks2 + 1 == 3) ? 0 : ks2 + 1;
    }

    #pragma unroll
    for (int n2 = 0; n2 < 4; ++n2) {
        #pragma unroll
        for (int r = 0; r < 4; ++r) {
            Op[(size_t)(qw + l4 * 4 + r) * HD + n2 * 16 + l15] = accO[n2][r];
        }
    }
}

extern "C" void kernel_launch(void* const* d_in, const int* in_sizes, int n_in,
                              void* d_out, int out_size, void* d_ws, size_t ws_size,
                              hipStream_t stream) {
    const float* Q = (const float*)d_in[0];
    const float* K = (const float*)d_in[1];
    const float* V = (const float*)d_in[2];
    const int*   M = (const int*)d_in[3];
    float* O = (float*)d_out;
    float* P = O + (size_t)2 * 16 * 2048 * 64;

    const size_t half = (size_t)32 * NITER * TILE_BYTES;            // 8 MB
    const size_t mb_bytes = (size_t)2 * NITER * SEQ * 8;            // 1 MB
    const int    smem_bytes = 6 * TILE_BYTES + 8 * 16 * BK * 4;     // 80 KB

    static bool attr_done = false;
    if (!attr_done) {
        (void)hipFuncSetAttribute(reinterpret_cast<const void*>(&attn_fwd<true>),
                                  hipFuncAttributeMaxDynamicSharedMemorySize, smem_bytes);
        (void)hipFuncSetAttribute(reinterpret_cast<const void*>(&attn_fwd<false>),
                                  hipFuncAttributeMaxDynamicSharedMemorySize, smem_bytes);
        attr_done = true;
    }

    short* Kb = (short*)d_ws;
    short* Vb = (short*)((char*)d_ws + half);
    prep_kv<<<dim3(NITER, 32), 256, 0, stream>>>(K, V, Kb, Vb);

    if (ws_size >= 2 * half + mb_bytes) {
        unsigned long long* MBp = (unsigned long long*)((char*)d_ws + 2 * half);
        prep_mask<<<1024, 256, 0, stream>>>(M, MBp);
        attn_fwd<true><<<dim3(SEQ / BQ, 32), 512, smem_bytes, stream>>>(Q, Kb, Vb, M, MBp, O, P);
    } else {
        attn_fwd<false><<<dim3(SEQ / BQ, 32), 512, smem_bytes, stream>>>(Q, Kb, Vb, M, nullptr, O, P);
    }
}

// Round 5
// 171.890 us; speedup vs baseline: 1.3796x; 1.0974x over previous
//
#include <hip/hip_runtime.h>

#define SEQ   2048
#define HD    64
#define BK    64
#define BQ    128
#define NITER (SEQ / BK)
#define K2E   0.18033688f          // 0.125 * log2(e), folded into Q fragments
#define TILE_BYTES 8192            // 64 x 64 bf16

typedef __attribute__((ext_vector_type(4))) float f32x4;
typedef __attribute__((ext_vector_type(8))) short bf16x8;
typedef unsigned long long u64;
typedef __attribute__((ext_vector_type(2))) unsigned long long u64x2;

#define SB() __builtin_amdgcn_sched_barrier(0)

// fp32 -> bf16 round-to-nearest-even
__device__ __forceinline__ short f2b(float f) {
    unsigned u = __builtin_bit_cast(unsigned, f);
    u += 0x7fffu + ((u >> 16) & 1u);
    return (short)(u >> 16);
}

// XOR-swizzle: 16B granule permuted within each 128B row (K/V images)
__device__ __forceinline__ unsigned swz(unsigned row, unsigned byteoff) {
    unsigned g = ((row & 7u) ^ ((row >> 3) & 7u)) << 4;
    return row * 128u + (byteoff ^ g);
}

// async global->LDS DMA, 16B per lane (dest = uniform base + lane*16)
__device__ __forceinline__ void async16(void* l, const void* g) {
    __builtin_amdgcn_global_load_lds(
        (const __attribute__((address_space(1))) unsigned int*)g,
        (__attribute__((address_space(3))) unsigned int*)l, 16, 0, 0);
}

// ============ prep: K,V fp32 -> bf16 swizzled per-tile images in ws ============
__global__ __launch_bounds__(256, 4)
void prep_kv(const float* __restrict__ Kg, const float* __restrict__ Vg,
             short* __restrict__ Kb, short* __restrict__ Vb)
{
    __shared__ short ldsv[BK * HD];
    const int tid = threadIdx.x;
    const int t   = blockIdx.x;
    const int bh  = blockIdx.y;
    const int rr  = tid >> 3;
    const int d0  = (tid & 7) * 8;

    const float* Kt = Kg + ((size_t)bh * SEQ + t * BK) * HD;
    const float* Vt = Vg + ((size_t)bh * SEQ + t * BK) * HD;
    short* Kout = Kb + ((size_t)bh * NITER + t) * (TILE_BYTES / 2);
    short* Vout = Vb + ((size_t)bh * NITER + t) * (TILE_BYTES / 2);

    #pragma unroll
    for (int h = 0; h < 2; ++h) {
        const int r = rr + h * 32;
        f32x4 a = *(const f32x4*)(Kt + (size_t)r * HD + d0);
        f32x4 b = *(const f32x4*)(Kt + (size_t)r * HD + d0 + 4);
        bf16x8 v;
        #pragma unroll
        for (int j = 0; j < 4; ++j) { v[j] = f2b(a[j]); v[4 + j] = f2b(b[j]); }
        *(bf16x8*)((char*)Kout + swz(r, 2 * d0)) = v;

        f32x4 c = *(const f32x4*)(Vt + (size_t)r * HD + d0);
        f32x4 d = *(const f32x4*)(Vt + (size_t)r * HD + d0 + 4);
        #pragma unroll
        for (int j = 0; j < 4; ++j) {
            *(short*)((char*)ldsv + swz(d0 + j,     2 * r)) = f2b(c[j]);
            *(short*)((char*)ldsv + swz(d0 + 4 + j, 2 * r)) = f2b(d[j]);
        }
    }
    __syncthreads();
    const int off = tid * 16;
    *(f32x4*)((char*)Vout + off)        = *(const f32x4*)((const char*)ldsv + off);
    *(f32x4*)((char*)Vout + off + 4096) = *(const f32x4*)((const char*)ldsv + off + 4096);
}

// ===== prep: mask int32 -> bitmap MB[b][it][q], bit j = mask[b][q][it*64+j] =====
__global__ __launch_bounds__(256, 4)
void prep_mask(const int* __restrict__ Mg, unsigned long long* __restrict__ MB)
{
    const int tid  = threadIdx.x;
    const int lane = tid & 63;
    const int wv   = blockIdx.x * 4 + (tid >> 6);
    const int b    = wv >> 11;
    const int wvb  = wv & 2047;
    const int it   = wvb >> 6;
    const int qc   = (wvb & 63) * 32;
    const int k    = it * 64 + lane;

    const int* src = Mg + ((size_t)b * SEQ + qc) * SEQ + k;
    unsigned long long* dst = MB + ((size_t)b * NITER + it) * SEQ + qc;
    for (int i = 0; i < 32; ++i) {
        int mv = src[(size_t)i * SEQ];
        unsigned long long bits = __ballot(mv != 0);
        if (lane == 0) dst[i] = bits;
    }
}

// ================================ main kernel =================================
// 512 threads = 8 waves; each wave owns 16 q-rows (128 per block).
// Pass B: S^T via swapped MFMA -> f32x4 per lane -> LDS transpose -> full-line
// NT dwordx4 stores. K/V staged 2 iters ahead (3-deep each), vmcnt(11) steady.
// Per-block k-tile stagger (boff = nf & 31): co-resident blocks write different
// k-column windows concurrently -> spreads the 8KB-stride P stream across all
// HBM channels instead of one congruence class machine-wide.
template<bool USE_MB>
__global__ __launch_bounds__(512, 4)
void attn_fwd(const float* __restrict__ Qg, const short* __restrict__ Kb,
              const short* __restrict__ Vb, const int* __restrict__ Mg,
              const unsigned long long* __restrict__ MB,
              float* __restrict__ Og, float* __restrict__ Pg)
{
    extern __shared__ char smem[];                       // 81920 B dynamic
    short (*lds_kv)[BK * HD] = (short (*)[BK * HD])smem;          // 6 x 8KB
    float (*lds_ps)[16 * BK] = (float (*)[16 * BK])(smem + 6 * TILE_BYTES); // 8 x 4KB

    const int tid  = threadIdx.x;
    const int w    = tid >> 6;
    const int lane = tid & 63;
    const int l15  = lane & 15;
    const int l4   = lane >> 4;

    // XCD-aware bijective swizzle: 512 blocks -> 4 consecutive bh per XCD
    const int flat = blockIdx.x + (blockIdx.y << 4);
    const int nf   = ((flat & 7) << 6) | (flat >> 3);
    const int bh   = nf >> 4;
    const int qblk = nf & 15;
    const int b    = bh >> 4;
    const int qw   = qblk * BQ + w * 16;
    const int boff = nf & 31;      // pass-B k-tile stagger

    const float* Qp = Qg + (size_t)bh * SEQ * HD;
    const char*  Kt = (const char*)(Kb + (size_t)bh * NITER * (TILE_BYTES / 2));
    const char*  Vt = (const char*)(Vb + (size_t)bh * NITER * (TILE_BYTES / 2));
    const int*   Mp = Mg + (size_t)b * SEQ * SEQ;
    float*       Op = Og + (size_t)bh * SEQ * HD;
    float*       Pp = Pg + (size_t)bh * SEQ * SEQ;
    const u64*   MBq  = USE_MB ? MB + (size_t)b * NITER * SEQ + (qw + l4 * 4) : nullptr;
    const u64*   MBrw = USE_MB ? MB + (size_t)b * NITER * SEQ + (qw + l15)    : nullptr;

    // Q fragments pre-scaled by K2E: row qw+l15, k-dim d = c*32 + l4*8 + j
    bf16x8 qf[2];
    {
        const float* qrow = Qp + (size_t)(qw + l15) * HD + l4 * 8;
        #pragma unroll
        for (int c = 0; c < 2; ++c) {
            bf16x8 v;
            #pragma unroll
            for (int j = 0; j < 8; ++j) v[j] = f2b(qrow[c * 32 + j] * K2E);
            qf[c] = v;
        }
    }

    const int* mrow[4];
    #pragma unroll
    for (int r = 0; r < 4; ++r)
        mrow[r] = Mp + (size_t)(qw + l4 * 4 + r) * SEQ + l15;

    // 8 waves x 1KB = one 8KB tile per stage; exactly ONE VMEM op per wave
    auto stage_tile = [&](const char* gbase, int slot, int it) {
        const char* g = gbase + (size_t)it * TILE_BYTES + w * 1024 + lane * 16;
        char* l = (char*)lds_kv[slot] + w * 1024;
        async16(l, g);
    };

    // ---- pass A gate words: rows qw + l4*4 + r (4 u64 per lane) ----
    u64 curW[4], nxtW[4];
    auto loadW = [&](int it, u64* dst) {
        if constexpr (USE_MB) {
            const u64* mp = MBq + (size_t)it * SEQ;
            u64x2 a = *(const u64x2*)mp;
            u64x2 c = *(const u64x2*)(mp + 2);
            dst[0] = a[0]; dst[1] = a[1]; dst[2] = c[0]; dst[3] = c[1];
        }
    };
    unsigned gbit[4][4];   // pass A: [r][n]
    auto extract = [&](const u64* ws_, int it) {
        if constexpr (USE_MB) {
            #pragma unroll
            for (int r = 0; r < 4; ++r) {
                u64 wr = ws_[r] >> l15;
                unsigned lo = (unsigned)wr, hi = (unsigned)(wr >> 32);
                gbit[r][0] = lo & 1u;
                gbit[r][1] = lo & 0x10000u;
                gbit[r][2] = hi & 1u;
                gbit[r][3] = hi & 0x10000u;
            }
        } else {
            const int k0 = it * BK;
            #pragma unroll
            for (int r = 0; r < 4; ++r)
                #pragma unroll
                for (int n = 0; n < 4; ++n)
                    gbit[r][n] = (mrow[r][k0 + n * 16] != 0);
        }
    };
    auto rotW = [&]() {
        #pragma unroll
        for (int r = 0; r < 4; ++r) curW[r] = nxtW[r];
    };

    float lsum[4] = {0.f, 0.f, 0.f, 0.f};

    // ========== pass A: per-row denom, pinned 3-deep K pipeline ================
    stage_tile(Kt, 0, 0);           SB();
    loadW(0, curW);                 SB();
    stage_tile(Kt, 1, 1);           SB();
    stage_tile(Kt, 2, 2);           SB();
    for (int it = 0; it < NITER; ++it) {
        if constexpr (USE_MB) {
            if (it == 0)              asm volatile("s_waitcnt vmcnt(2)" ::: "memory");
            else if (it < NITER - 2)  asm volatile("s_waitcnt vmcnt(1)" ::: "memory");
            else                      asm volatile("s_waitcnt vmcnt(0)" ::: "memory");
        } else {
            if (it < NITER - 2)       asm volatile("s_waitcnt vmcnt(2)" ::: "memory");
            else if (it == NITER - 2) asm volatile("s_waitcnt vmcnt(1)" ::: "memory");
            else                      asm volatile("s_waitcnt vmcnt(0)" ::: "memory");
        }
        __builtin_amdgcn_s_barrier();
        SB();
        if (it + 1 < NITER) loadW(it + 1, nxtW);
        SB();
        if (it + 3 < NITER) stage_tile(Kt, (it + 3) & 3, it + 3);
        SB();

        extract(curW, it);

        const char* kbase = (const char*)lds_kv[it & 3];
        f32x4 sA[4];
        #pragma unroll
        for (int n = 0; n < 4; ++n) {
            f32x4 acc = {0.f, 0.f, 0.f, 0.f};
            #pragma unroll
            for (int c = 0; c < 2; ++c) {
                bf16x8 kf = *(const bf16x8*)(kbase +
                                swz(n * 16 + l15, (unsigned)(c * 64 + l4 * 16)));
                acc = __builtin_amdgcn_mfma_f32_16x16x32_bf16(qf[c], kf, acc, 0, 0, 0);
            }
            sA[n] = acc;
        }
        #pragma unroll
        for (int r = 0; r < 4; ++r) {
            #pragma unroll
            for (int n = 0; n < 4; ++n) {
                float e = exp2f(sA[n][r]);
                lsum[r] += gbit[r][n] ? e : 0.f;
            }
        }
        rotW();
    }

    // single cross-lane reduce; fold 1/l as additive -log2(l)
    float cl[4];
    #pragma unroll
    for (int r = 0; r < 4; ++r) {
        float s = lsum[r];
        s += __shfl_xor(s, 1);
        s += __shfl_xor(s, 2);
        s += __shfl_xor(s, 4);
        s += __shfl_xor(s, 8);
        cl[r] = -log2f(s);
    }
    // broadcast: clb = cl for q-row (qw + l15); source lane l4' = l15>>2, reg = l15&3
    float clb;
    {
        const int src = (l15 >> 2) << 4;
        float t0 = __shfl(cl[0], src);
        float t1 = __shfl(cl[1], src);
        float t2 = __shfl(cl[2], src);
        float t3 = __shfl(cl[3], src);
        float ca = (l15 & 1) ? t1 : t0;
        float cb = (l15 & 1) ? t3 : t2;
        clb = (l15 & 2) ? cb : ca;
    }

    f32x4 accO[4];
    #pragma unroll
    for (int n = 0; n < 4; ++n) accO[n] = (f32x4){0.f, 0.f, 0.f, 0.f};

    // ========== pass B: S^T recompute, LDS transpose, NT stores, O = P.V =======
    // 3-deep K (slots 0..2) + 3-deep V (slots 3..5), staged 2 iters ahead.
    // Tile order staggered by boff per block; k-sum is commutative.
    u64 gA = 0, gB = 0, gC = 0;
    auto loadB = [&](int it, u64& d) {
        if constexpr (USE_MB) d = *(const u64*)(MBrw + (size_t)it * SEQ);
    };
    unsigned gb[4][4];   // pass B: [n][r], k = n*16 + l4*4 + r of q-row (qw+l15)
    auto extractB = [&](u64 wd, int it) {
        if constexpr (USE_MB) {
            #pragma unroll
            for (int r = 0; r < 4; ++r) {
                u64 wr = wd >> (l4 * 4 + r);
                unsigned lo = (unsigned)wr, hi = (unsigned)(wr >> 32);
                gb[0][r] = lo & 1u;
                gb[1][r] = lo & 0x10000u;
                gb[2][r] = hi & 1u;
                gb[3][r] = hi & 0x10000u;
            }
        } else {
            const int* mB = Mp + (size_t)(qw + l15) * SEQ + l4 * 4 + it * BK;
            #pragma unroll
            for (int n = 0; n < 4; ++n)
                #pragma unroll
                for (int r = 0; r < 4; ++r)
                    gb[n][r] = (mB[n * 16 + r] != 0);
        }
    };

    char* psb = (char*)lds_ps[w];

    int ks  = 0;   // slot of current iter (mod 3)
    int ks2 = 2;   // slot for staging it+2

    {
        const int t0 = boff;
        const int t1 = (boff + 1) & (NITER - 1);
        loadB(t0, gA);                  SB();
        stage_tile(Kt, 0, t0);          SB();
        stage_tile(Vt, 3, t0);          SB();
        loadB(t1, gB);                  SB();
        stage_tile(Kt, 1, t1);          SB();
        stage_tile(Vt, 4, t1);          SB();
    }
    if constexpr (USE_MB) asm volatile("s_waitcnt vmcnt(3)" ::: "memory");
    else                  asm volatile("s_waitcnt vmcnt(2)" ::: "memory");
    __builtin_amdgcn_s_barrier();
    SB();
    for (int it = 0; it < NITER; ++it) {
        const int itb = (it + boff) & (NITER - 1);
        const int k0  = itb * BK;
        if (it + 2 < NITER) {
            const int itp = (it + 2 + boff) & (NITER - 1);
            loadB(itp, gC);                   SB();
            stage_tile(Kt, ks2, itp);         SB();
            stage_tile(Vt, 3 + ks2, itp);
        }
        SB();

        extractB(gA, itb);

        // S^T: mfma(K, Q) -> col = q-row (l15), row = k-index (l4*4 + reg)
        const char* kbase = (const char*)lds_kv[ks];
        f32x4 sA[4];
        #pragma unroll
        for (int n = 0; n < 4; ++n) {
            f32x4 acc = {0.f, 0.f, 0.f, 0.f};
            #pragma unroll
            for (int c = 0; c < 2; ++c) {
                bf16x8 kf = *(const bf16x8*)(kbase +
                                swz(n * 16 + l15, (unsigned)(c * 64 + l4 * 16)));
                acc = __builtin_amdgcn_mfma_f32_16x16x32_bf16(kf, qf[c], acc, 0, 0, 0);
            }
            sA[n] = acc;
        }

        // p quads -> fp32 LDS (row = l15, granule (n*4+l4) ^ row)
        #pragma unroll
        for (int n = 0; n < 4; ++n) {
            f32x4 pq;
            #pragma unroll
            for (int r = 0; r < 4; ++r) {
                float e = exp2f(sA[n][r] + clb);
                pq[r] = gb[n][r] ? e : 0.f;
            }
            *(f32x4*)(psb + l15 * 256 +
                      ((((unsigned)(n * 4 + l4)) ^ (unsigned)l15) << 4)) = pq;
        }
        asm volatile("s_waitcnt lgkmcnt(0)" ::: "memory");
        SB();

        // readback rows (i*4+l4), cols l15*4..+3 -> NT dwordx4: 256B/row segments
        f32x4 tq[4];
        #pragma unroll
        for (int i = 0; i < 4; ++i) {
            const unsigned row = (unsigned)(i * 4 + l4);
            tq[i] = *(const f32x4*)(psb + row * 256 + (((unsigned)l15 ^ row) << 4));
        }
        #pragma unroll
        for (int i = 0; i < 4; ++i) {
            __builtin_nontemporal_store(tq[i],
                (f32x4*)(Pp + (size_t)(qw + i * 4 + l4) * SEQ + k0 + l15 * 4));
        }
        SB();

        // O(16x64) += P(16x64) . V(64x64); pf from fp32 staging + f2b
        const char* vbase = (const char*)lds_kv[3 + ks];
        #pragma unroll
        for (int c = 0; c < 2; ++c) {
            const unsigned gb0 = (unsigned)(c * 8 + l4 * 2);
            f32x4 pa = *(const f32x4*)(psb + l15 * 256 + ((gb0 ^ (unsigned)l15) << 4));
            f32x4 pb = *(const f32x4*)(psb + l15 * 256 + (((gb0 + 1u) ^ (unsigned)l15) << 4));
            bf16x8 pf;
            #pragma unroll
            for (int j = 0; j < 4; ++j) { pf[j] = f2b(pa[j]); pf[4 + j] = f2b(pb[j]); }
            #pragma unroll
            for (int n2 = 0; n2 < 4; ++n2) {
                bf16x8 vf = *(const bf16x8*)(vbase +
                                swz(n2 * 16 + l15, (unsigned)(c * 64 + l4 * 16)));
                accO[n2] = __builtin_amdgcn_mfma_f32_16x16x32_bf16(pf, vf, accO[n2], 0, 0, 0);
            }
        }
        SB();
        asm volatile("s_waitcnt lgkmcnt(0)" ::: "memory");
        if (it + 1 < NITER) {
            if (it == 0)              asm volatile("s_waitcnt vmcnt(7)"  ::: "memory");
            else if (it < NITER - 2)  asm volatile("s_waitcnt vmcnt(11)" ::: "memory");
            else                      asm volatile("s_waitcnt vmcnt(8)"  ::: "memory");
            __builtin_amdgcn_s_barrier();
        }
        SB();
        gA = gB; gB = gC;
        ks  = (ks  + 1 == 3) ? 0 : ks  + 1;
        ks2 = (ks2 + 1 == 3) ? 0 : ks2 + 1;
    }

    #pragma unroll
    for (int n2 = 0; n2 < 4; ++n2) {
        #pragma unroll
        for (int r = 0; r < 4; ++r) {
            Op[(size_t)(qw + l4 * 4 + r) * HD + n2 * 16 + l15] = accO[n2][r];
        }
    }
}

extern "C" void kernel_launch(void* const* d_in, const int* in_sizes, int n_in,
                              void* d_out, int out_size, void* d_ws, size_t ws_size,
                              hipStream_t stream) {
    const float* Q = (const float*)d_in[0];
    const float* K = (const float*)d_in[1];
    const float* V = (const float*)d_in[2];
    const int*   M = (const int*)d_in[3];
    float* O = (float*)d_out;
    float* P = O + (size_t)2 * 16 * 2048 * 64;

    const size_t half = (size_t)32 * NITER * TILE_BYTES;            // 8 MB
    const size_t mb_bytes = (size_t)2 * NITER * SEQ * 8;            // 1 MB
    const int    smem_bytes = 6 * TILE_BYTES + 8 * 16 * BK * 4;     // 80 KB

    static bool attr_done = false;
    if (!attr_done) {
        (void)hipFuncSetAttribute(reinterpret_cast<const void*>(&attn_fwd<true>),
                                  hipFuncAttributeMaxDynamicSharedMemorySize, smem_bytes);
        (void)hipFuncSetAttribute(reinterpret_cast<const void*>(&attn_fwd<false>),
                                  hipFuncAttributeMaxDynamicSharedMemorySize, smem_bytes);
        attr_done = true;
    }

    short* Kb = (short*)d_ws;
    short* Vb = (short*)((char*)d_ws + half);
    prep_kv<<<dim3(NITER, 32), 256, 0, stream>>>(K, V, Kb, Vb);

    if (ws_size >= 2 * half + mb_bytes) {
        unsigned long long* MBp = (unsigned long long*)((char*)d_ws + 2 * half);
        prep_mask<<<1024, 256, 0, stream>>>(M, MBp);
        attn_fwd<true><<<dim3(SEQ / BQ, 32), 512, smem_bytes, stream>>>(Q, Kb, Vb, M, MBp, O, P);
    } else {
        attn_fwd<false><<<dim3(SEQ / BQ, 32), 512, smem_bytes, stream>>>(Q, Kb, Vb, M, nullptr, O, P);
    }
}